// Round 7
// baseline (504.736 us; speedup 1.0000x reference)
//
#include <hip/hip_runtime.h>

#define N_NODES 100000
#define N_EDGES 3200000
#define F_IN 128
#define F_OUT 16

#define NSEG 256                 // binning segments
#define EPS (N_EDGES / NSEG)     // 12500 edges/segment (exact)
#define NBUCK 2048               // destination buckets
#define NPB 49                   // nodes per bucket: 49*2048 = 100352 >= N
#define GEMM_BLOCKS ((N_NODES + 15) / 16)   // 6250
#define ASTRIDE 17               // padded acc stride (bank-conflict break)
#define MAXREC 2048              // staged records per bucket (mean 1568, sigma ~40)

// ---- ws layout (bytes) ----
#define OFF_TT    0u            // NBUCK*NSEG ints = 2 MB (T_t[b][s], stride NSEG)
#define OFF_TOT   0x200000u     // NBUCK ints (bucket totals)
#define OFF_BASE  0x202000u     // NBUCK ints (bucket base offsets)
#define OFF_DINV  0x210000u     // N floats (400 KB)
#define OFF_HH    0x300000u     // N*16 floats (6.4 MB)
#define OFF_GG    0x920000u     // N*16 floats (6.4 MB)
#define OFF_CSR   0x1000000u    // E int2 (25.6 MB)
#define WS_NEEDED ((size_t)0x1000000 + (size_t)N_EDGES * 8)

// ============ main path (no global atomics) ============

// K1: per-segment LDS histogram of dest buckets  +  co-scheduled h = x@W
__global__ void k_hist_gemm(const int* __restrict__ col,
                            int* __restrict__ Tt,
                            const float* __restrict__ x,
                            const float* __restrict__ W,
                            float* __restrict__ h) {
    __shared__ int smem[2048];   // hist bins OR 8KB W staging
    int tid = threadIdx.x;
    if (blockIdx.x < NSEG) {
        int s = blockIdx.x;
        for (int i = tid; i < NBUCK; i += 256) smem[i] = 0;
        __syncthreads();
        int e0 = s * EPS;
        for (int i = tid; i < EPS; i += 256)
            atomicAdd(&smem[col[e0 + i] / NPB], 1);
        __syncthreads();
        for (int i = tid; i < NBUCK; i += 256)
            Tt[(size_t)i * NSEG + s] = smem[i];
    } else {
        float* Ws = (float*)smem;
        for (int i = tid; i < F_IN * F_OUT; i += 256) Ws[i] = W[i];
        __syncthreads();
        int n = (blockIdx.x - NSEG) * 16 + (tid >> 4);
        int j = tid & 15;
        if (n >= N_NODES) return;
        const float4* xr = (const float4*)(x + (size_t)n * F_IN);
        float acc = 0.0f;
#pragma unroll
        for (int k4 = 0; k4 < F_IN / 4; ++k4) {
            float4 xv = xr[k4];
            int k = k4 * 4;
            acc += xv.x * Ws[(k + 0) * F_OUT + j];
            acc += xv.y * Ws[(k + 1) * F_OUT + j];
            acc += xv.z * Ws[(k + 2) * F_OUT + j];
            acc += xv.w * Ws[(k + 3) * F_OUT + j];
        }
        h[(size_t)n * F_OUT + j] = acc;
    }
}

// K2: wave per bucket — exclusive scan of its NSEG counts (int4 coalesced)
__global__ void k_scan_a(int* __restrict__ Tt, int* __restrict__ tot) {
    int tid = threadIdx.x;
    int b = blockIdx.x * 4 + (tid >> 6);     // 4 waves/block
    int l = tid & 63;
    int4* row = (int4*)Tt + (size_t)b * (NSEG / 4);
    int4 v = row[l];
    int sum = v.x + v.y + v.z + v.w;
    int pre = sum;
    for (int off = 1; off < 64; off <<= 1) {
        int t = __shfl_up(pre, off);
        if (l >= off) pre += t;
    }
    int excl = pre - sum;
    int4 o;
    o.x = excl;
    o.y = excl + v.x;
    o.z = o.y + v.y;
    o.w = o.z + v.z;
    row[l] = o;
    if (l == 63) tot[b] = excl + sum;
}

// K3: single block — exclusive scan of NBUCK totals -> base
__global__ void k_scan_b(const int* __restrict__ tot, int* __restrict__ base) {
    __shared__ int s[256];
    int tid = threadIdx.x;
    const int4* t4 = (const int4*)tot;
    int4 p = t4[tid * 2], q = t4[tid * 2 + 1];
    int lsum = p.x + p.y + p.z + p.w + q.x + q.y + q.z + q.w;
    s[tid] = lsum;
    __syncthreads();
    for (int off = 1; off < 256; off <<= 1) {
        int t = (tid >= off) ? s[tid - off] : 0;
        __syncthreads();
        s[tid] += t;
        __syncthreads();
    }
    int run = s[tid] - lsum;
    int4 o1, o2;
    o1.x = run; run += p.x;
    o1.y = run; run += p.y;
    o1.z = run; run += p.z;
    o1.w = run; run += p.w;
    o2.x = run; run += q.x;
    o2.y = run; run += q.y;
    o2.z = run; run += q.z;
    o2.w = run;
    int4* b4 = (int4*)base;
    b4[tid * 2] = o1;
    b4[tid * 2 + 1] = o2;
}

// K4: per-segment binning via LDS cursors; plain scattered 8B stores
__global__ void __launch_bounds__(512) k_bin(const int* __restrict__ row,
                                             const int* __restrict__ col,
                                             const float* __restrict__ ew,
                                             const int* __restrict__ Tt,
                                             const int* __restrict__ base,
                                             int2* __restrict__ csr) {
    __shared__ int cur[NBUCK];
    int tid = threadIdx.x;
    int s = blockIdx.x;
    for (int i = tid; i < NBUCK; i += 512)
        cur[i] = base[i] + Tt[(size_t)i * NSEG + s];
    __syncthreads();
    int e0 = s * EPS;
    for (int i = tid; i < EPS; i += 512) {
        int e = e0 + i;
        int r = row[e];
        int c = col[e];
        int bk = c / NPB;
        int pos = atomicAdd(&cur[bk], 1);      // LDS atomic
        int2 rec;
        rec.x = (r << 7) | (c - bk * NPB);
        rec.y = __float_as_int(ew[e]);
        csr[pos] = rec;
    }
}

// K5: per-bucket degree from contiguous records (LDS), dinv, g = dinv*h
__global__ void k_deg_g(const int* __restrict__ base,
                        const int* __restrict__ tot,
                        const int2* __restrict__ csr,
                        const float* __restrict__ h,
                        float* __restrict__ dinv,
                        float* __restrict__ g) {
    __shared__ float dl[64];
    int tid = threadIdx.x;
    int b = blockIdx.x;
    int c0 = b * NPB;
    if (tid < NPB) dl[tid] = 1.0f;             // self-loop weight
    __syncthreads();
    int p0 = base[b], p1 = p0 + tot[b];
    for (int i = p0 + tid; i < p1; i += 256) {
        int2 rec = csr[i];
        atomicAdd(&dl[rec.x & 127], __int_as_float(rec.y));   // LDS atomic
    }
    __syncthreads();
    if (tid < NPB) {
        float d = rsqrtf(dl[tid]);
        dl[tid] = d;
        int n = c0 + tid;
        if (n < N_NODES) dinv[n] = d;
    }
    __syncthreads();
    for (int i = tid; i < NPB * F_OUT; i += 256) {
        int idx = c0 * F_OUT + i;
        if (idx < N_NODES * F_OUT) g[idx] = dl[i >> 4] * h[idx];
    }
}

// K6: per-bucket pull — STAGE the bucket's contiguous csr slice into LDS in one
// coalesced burst (breaks the csr->gather dependent-latency chain that pinned
// R5/R6 at 268 us), then process from LDS: ds_read (broadcast) + independent
// L2/L3 gather + LDS-atomic accumulate. Zero global atomics.
__global__ void k_pull(const int* __restrict__ base,
                       const int* __restrict__ tot,
                       const int2* __restrict__ csr,
                       const float* __restrict__ g,
                       const float* __restrict__ dinv,
                       const float* __restrict__ bias,
                       float* __restrict__ out) {
    __shared__ int2 srec[MAXREC];          // 16 KB
    __shared__ float acc[NPB * ASTRIDE];   // 3332 B
    __shared__ float dl[64];
    int tid = threadIdx.x;
    int b = blockIdx.x;
    int c0 = b * NPB;
    for (int i = tid; i < NPB * ASTRIDE; i += 256) acc[i] = 0.0f;
    if (tid < NPB) {
        int n = c0 + tid;
        dl[tid] = (n < N_NODES) ? dinv[n] : 0.0f;
    }
    int p0 = base[b];
    int cnt = tot[b];
    int nstage = (cnt < MAXREC) ? cnt : MAXREC;
    // coalesced staging burst: independent loads, one latency exposure
    for (int i = tid; i < nstage; i += 256) srec[i] = csr[p0 + i];
    __syncthreads();

    int q = tid & 3;
    // main loop: ds_read (4 lanes broadcast) + one independent float4 gather
#pragma unroll 2
    for (int i = (tid >> 2); i < nstage; i += 64) {
        int2 rec = srec[i];
        int cl = rec.x & 127;
        int r = rec.x >> 7;
        float w = __int_as_float(rec.y);
        float4 v = ((const float4*)(g + (size_t)r * F_OUT))[q];
        float* ab = acc + cl * ASTRIDE + q * 4;
        atomicAdd(&ab[0], v.x * w);
        atomicAdd(&ab[1], v.y * w);
        atomicAdd(&ab[2], v.z * w);
        atomicAdd(&ab[3], v.w * w);
    }
    // overflow remainder (statistically never: 12 sigma) — process from global
    for (int i = nstage + (tid >> 2); i < cnt; i += 64) {
        int2 rec = csr[p0 + i];
        int cl = rec.x & 127;
        int r = rec.x >> 7;
        float w = __int_as_float(rec.y);
        float4 v = ((const float4*)(g + (size_t)r * F_OUT))[q];
        float* ab = acc + cl * ASTRIDE + q * 4;
        atomicAdd(&ab[0], v.x * w);
        atomicAdd(&ab[1], v.y * w);
        atomicAdd(&ab[2], v.z * w);
        atomicAdd(&ab[3], v.w * w);
    }
    __syncthreads();
    for (int i = tid; i < NPB * F_OUT; i += 256) {
        int idx = c0 * F_OUT + i;
        if (idx < N_NODES * F_OUT) {
            int j = i & 15;
            int cl = i >> 4;
            out[idx] = bias[j] + dl[cl] * (g[idx] + acc[cl * ASTRIDE + j]);
        }
    }
}

// ============ fallback path (R4, proven) ============

#define EDGE_BLOCKS_FB ((N_EDGES + 255) / 256)
__global__ void k_init_fb(float* __restrict__ deg) {
    int i = blockIdx.x * blockDim.x + threadIdx.x;
    if (i < N_NODES) deg[i] = 1.0f;
}
__global__ void k_fused_fb(const int* __restrict__ col, const float* __restrict__ ew,
                           float* __restrict__ deg, const float* __restrict__ x,
                           const float* __restrict__ W, float* __restrict__ h) {
    int b3 = blockIdx.x / 3;
    int r3 = blockIdx.x % 3;
    if (r3 < 2) {
        int e = (b3 * 2 + r3) * 256 + threadIdx.x;
        if (e < N_EDGES) atomicAdd(&deg[col[e]], ew[e]);
    } else {
        __shared__ float Ws[F_IN * F_OUT];
        int tid = threadIdx.x;
        for (int i = tid; i < F_IN * F_OUT; i += 256) Ws[i] = W[i];
        __syncthreads();
        int n = b3 * 16 + (tid >> 4);
        int j = tid & 15;
        if (n >= N_NODES) return;
        const float4* xr = (const float4*)(x + (size_t)n * F_IN);
        float acc = 0.0f;
#pragma unroll
        for (int k4 = 0; k4 < F_IN / 4; ++k4) {
            float4 xv = xr[k4];
            int k = k4 * 4;
            acc += xv.x * Ws[(k + 0) * F_OUT + j];
            acc += xv.y * Ws[(k + 1) * F_OUT + j];
            acc += xv.z * Ws[(k + 2) * F_OUT + j];
            acc += xv.w * Ws[(k + 3) * F_OUT + j];
        }
        h[(size_t)n * F_OUT + j] = acc;
    }
}
__global__ void k_final_fb(float* __restrict__ deg, const float* __restrict__ h,
                           const float* __restrict__ b, float* __restrict__ g,
                           float* __restrict__ out) {
    int i = blockIdx.x * blockDim.x + threadIdx.x;
    int n = i >> 4;
    int j = i & 15;
    if (n >= N_NODES) return;
    float d = rsqrtf(deg[n]);
    if (j == 0) deg[n] = d;
    float gg = d * h[i];
    g[i] = gg;
    out[i] = b[j] + d * gg;
}
__global__ void k_scatter_fb(const int* __restrict__ row, const int* __restrict__ col,
                             const float* __restrict__ ew, const float* __restrict__ dinv,
                             const float* __restrict__ g, float* __restrict__ out) {
    long long tid = (long long)blockIdx.x * blockDim.x + threadIdx.x;
    int e = (int)(tid >> 4);
    int j = (int)(tid & 15);
    if (e >= N_EDGES) return;
    int c = col[e];
    float norm = ew[e] * dinv[c];
    atomicAdd(&out[(size_t)c * F_OUT + j], g[(size_t)row[e] * F_OUT + j] * norm);
}

extern "C" void kernel_launch(void* const* d_in, const int* in_sizes, int n_in,
                              void* d_out, int out_size, void* d_ws, size_t ws_size,
                              hipStream_t stream) {
    const float* x  = (const float*)d_in[0];
    const int*   ei = (const int*)d_in[1];   // [2, N_EDGES] int32
    const float* ew = (const float*)d_in[2];
    const float* W  = (const float*)d_in[3];
    const float* b  = (const float*)d_in[4];
    float* out = (float*)d_out;

    const int* row = ei;            // edge_index[0] = source
    const int* col = ei + N_EDGES;  // edge_index[1] = destination

    char* ws = (char*)d_ws;
    dim3 blk(256);

    if (ws_size >= WS_NEEDED) {
        int*   Tt   = (int*)(ws + OFF_TT);
        int*   tot  = (int*)(ws + OFF_TOT);
        int*   base = (int*)(ws + OFF_BASE);
        float* dinv = (float*)(ws + OFF_DINV);
        float* h    = (float*)(ws + OFF_HH);
        float* g    = (float*)(ws + OFF_GG);
        int2*  csr  = (int2*)(ws + OFF_CSR);

        k_hist_gemm<<<NSEG + GEMM_BLOCKS, blk, 0, stream>>>(col, Tt, x, W, h);
        k_scan_a<<<NBUCK / 4, blk, 0, stream>>>(Tt, tot);
        k_scan_b<<<1, blk, 0, stream>>>(tot, base);
        k_bin<<<NSEG, 512, 0, stream>>>(row, col, ew, Tt, base, csr);
        k_deg_g<<<NBUCK, blk, 0, stream>>>(base, tot, csr, h, dinv, g);
        k_pull<<<NBUCK, blk, 0, stream>>>(base, tot, csr, g, dinv, b, out);
    } else {
        float* deg = (float*)ws;
        float* h   = (float*)(ws + (1u << 20));
        float* g   = (float*)(ws + (8u << 20));
        k_init_fb<<<(N_NODES + 255) / 256, blk, 0, stream>>>(deg);
        k_fused_fb<<<EDGE_BLOCKS_FB + GEMM_BLOCKS, blk, 0, stream>>>(col, ew, deg, x, W, h);
        k_final_fb<<<(N_NODES * F_OUT + 255) / 256, blk, 0, stream>>>(deg, h, b, g, out);
        long long total = (long long)N_EDGES * F_OUT;
        k_scatter_fb<<<(unsigned)((total + 255) / 256), blk, 0, stream>>>(row, col, ew, deg, g, out);
    }
}

// Round 8
// 300.454 us; speedup vs baseline: 1.6799x; 1.6799x over previous
//
#include <hip/hip_runtime.h>

#define N_NODES 100000
#define N_EDGES 3200000
#define F_IN 128
#define F_OUT 16

#define NSEG 256                 // binning segments
#define EPS (N_EDGES / NSEG)     // 12500 edges/segment (exact)
#define NBUCK 2048               // destination buckets
#define NPB 49                   // nodes per bucket: 49*2048 = 100352 >= N
#define GEMM_BLOCKS ((N_NODES + 15) / 16)   // 6250
#define MAXREC 2048              // staged records per bucket (mean 1563, +12 sigma)

// ---- ws layout (bytes) ----
#define OFF_TT    0u            // NBUCK*NSEG ints = 2 MB; DEAD after k_bin -> reused as ncnt
#define OFF_NCNT  0u            // N ints (400 KB), written by k_sort
#define OFF_TOT   0x200000u     // NBUCK ints
#define OFF_BASE  0x202000u     // NBUCK ints
#define OFF_DINV  0x210000u     // N floats (400 KB)
#define OFF_NPTR  0x280000u     // N ints (400 KB)
#define OFF_HH    0x300000u     // N*16 floats (6.4 MB)
#define OFF_GG    0x920000u     // N*16 floats (6.4 MB)
#define OFF_CSR   0x1000000u    // E int2 (25.6 MB); sorted IN PLACE by k_sort
#define WS_NEEDED ((size_t)0x1000000 + (size_t)N_EDGES * 8)

// ============ main path (no global atomics) ============

// K1: per-segment LDS histogram of dest buckets  +  co-scheduled h = x@W
__global__ void k_hist_gemm(const int* __restrict__ col,
                            int* __restrict__ Tt,
                            const float* __restrict__ x,
                            const float* __restrict__ W,
                            float* __restrict__ h) {
    __shared__ int smem[2048];   // hist bins OR 8KB W staging
    int tid = threadIdx.x;
    if (blockIdx.x < NSEG) {
        int s = blockIdx.x;
        for (int i = tid; i < NBUCK; i += 256) smem[i] = 0;
        __syncthreads();
        int e0 = s * EPS;
        for (int i = tid; i < EPS; i += 256)
            atomicAdd(&smem[col[e0 + i] / NPB], 1);
        __syncthreads();
        for (int i = tid; i < NBUCK; i += 256)
            Tt[(size_t)i * NSEG + s] = smem[i];
    } else {
        float* Ws = (float*)smem;
        for (int i = tid; i < F_IN * F_OUT; i += 256) Ws[i] = W[i];
        __syncthreads();
        int n = (blockIdx.x - NSEG) * 16 + (tid >> 4);
        int j = tid & 15;
        if (n >= N_NODES) return;
        const float4* xr = (const float4*)(x + (size_t)n * F_IN);
        float acc = 0.0f;
#pragma unroll
        for (int k4 = 0; k4 < F_IN / 4; ++k4) {
            float4 xv = xr[k4];
            int k = k4 * 4;
            acc += xv.x * Ws[(k + 0) * F_OUT + j];
            acc += xv.y * Ws[(k + 1) * F_OUT + j];
            acc += xv.z * Ws[(k + 2) * F_OUT + j];
            acc += xv.w * Ws[(k + 3) * F_OUT + j];
        }
        h[(size_t)n * F_OUT + j] = acc;
    }
}

// K2: wave per bucket — exclusive scan of its NSEG counts (int4 coalesced)
__global__ void k_scan_a(int* __restrict__ Tt, int* __restrict__ tot) {
    int tid = threadIdx.x;
    int b = blockIdx.x * 4 + (tid >> 6);     // 4 waves/block
    int l = tid & 63;
    int4* row = (int4*)Tt + (size_t)b * (NSEG / 4);
    int4 v = row[l];
    int sum = v.x + v.y + v.z + v.w;
    int pre = sum;
    for (int off = 1; off < 64; off <<= 1) {
        int t = __shfl_up(pre, off);
        if (l >= off) pre += t;
    }
    int excl = pre - sum;
    int4 o;
    o.x = excl;
    o.y = excl + v.x;
    o.z = o.y + v.y;
    o.w = o.z + v.z;
    row[l] = o;
    if (l == 63) tot[b] = excl + sum;
}

// K3: single block — exclusive scan of NBUCK totals -> base
__global__ void k_scan_b(const int* __restrict__ tot, int* __restrict__ base) {
    __shared__ int s[256];
    int tid = threadIdx.x;
    const int4* t4 = (const int4*)tot;
    int4 p = t4[tid * 2], q = t4[tid * 2 + 1];
    int lsum = p.x + p.y + p.z + p.w + q.x + q.y + q.z + q.w;
    s[tid] = lsum;
    __syncthreads();
    for (int off = 1; off < 256; off <<= 1) {
        int t = (tid >= off) ? s[tid - off] : 0;
        __syncthreads();
        s[tid] += t;
        __syncthreads();
    }
    int run = s[tid] - lsum;
    int4 o1, o2;
    o1.x = run; run += p.x;
    o1.y = run; run += p.y;
    o1.z = run; run += p.z;
    o1.w = run; run += p.w;
    o2.x = run; run += q.x;
    o2.y = run; run += q.y;
    o2.z = run; run += q.z;
    o2.w = run;
    int4* b4 = (int4*)base;
    b4[tid * 2] = o1;
    b4[tid * 2 + 1] = o2;
}

// K4: per-segment binning via LDS cursors; records: ((r<<7)|c_local, ew)
__global__ void __launch_bounds__(512) k_bin(const int* __restrict__ row,
                                             const int* __restrict__ col,
                                             const float* __restrict__ ew,
                                             const int* __restrict__ Tt,
                                             const int* __restrict__ base,
                                             int2* __restrict__ csr) {
    __shared__ int cur[NBUCK];
    int tid = threadIdx.x;
    int s = blockIdx.x;
    for (int i = tid; i < NBUCK; i += 512)
        cur[i] = base[i] + Tt[(size_t)i * NSEG + s];
    __syncthreads();
    int e0 = s * EPS;
    for (int i = tid; i < EPS; i += 512) {
        int e = e0 + i;
        int r = row[e];
        int c = col[e];
        int bk = c / NPB;
        int pos = atomicAdd(&cur[bk], 1);      // LDS atomic
        int2 rec;
        rec.x = (r << 7) | (c - bk * NPB);
        rec.y = __float_as_int(ew[e]);
        csr[pos] = rec;
    }
}

// K5: per-bucket — stage slice to LDS; per-node count + weight-sum; scan;
// dinv + g = dinv*h; nodeptr/ncnt; IN-PLACE scatter sorted by dest node,
// stripping c_local (records become (r, w)). Overflow buckets (> MAXREC,
// statistically never) are left unsorted and flagged via negative ncnt.
__global__ void k_sort(const int* __restrict__ base,
                       const int* __restrict__ tot,
                       int2* __restrict__ csr,
                       const float* __restrict__ h,
                       float* __restrict__ dinv,
                       float* __restrict__ g,
                       int* __restrict__ nodeptr,
                       int* __restrict__ ncnt) {
    __shared__ int2 srec[MAXREC];      // 16 KB
    __shared__ int cnt[NPB];
    __shared__ float wsum[NPB];
    __shared__ int cur[NPB];
    __shared__ float dl[NPB];
    int tid = threadIdx.x;
    int b = blockIdx.x;
    int c0 = b * NPB;
    int bseg = base[b];
    int total = tot[b];
    bool ovf = (total > MAXREC);
    int nstage = ovf ? MAXREC : total;

    if (tid < NPB) { cnt[tid] = 0; wsum[tid] = 1.0f; }   // self-loop weight
    __syncthreads();

    // stage + count (remainder counted from global)
    for (int i = tid; i < nstage; i += 256) {
        int2 rec = csr[bseg + i];
        srec[i] = rec;
        atomicAdd(&cnt[rec.x & 127], 1);
        atomicAdd(&wsum[rec.x & 127], __int_as_float(rec.y));
    }
    for (int i = nstage + tid; i < total; i += 256) {
        int2 rec = csr[bseg + i];
        atomicAdd(&cnt[rec.x & 127], 1);
        atomicAdd(&wsum[rec.x & 127], __int_as_float(rec.y));
    }
    __syncthreads();

    // wave 0: 49-element scan, dinv, nodeptr/ncnt
    if (tid < 64) {
        int l = tid;
        int v = (l < NPB) ? cnt[l] : 0;
        int incl = v;
        for (int off = 1; off < 64; off <<= 1) {
            int t = __shfl_up(incl, off);
            if (l >= off) incl += t;
        }
        int excl = incl - v;
        if (l < NPB) {
            cur[l] = excl;
            float d = rsqrtf(wsum[l]);
            dl[l] = d;
            int n = c0 + l;
            if (n < N_NODES) {
                dinv[n] = d;
                nodeptr[n] = ovf ? bseg : (bseg + excl);
                ncnt[n] = ovf ? -total : v;
            }
        }
    }
    __syncthreads();

    // in-place scatter (all reads were staged before this point)
    if (!ovf) {
        for (int i = tid; i < total; i += 256) {
            int2 rec = srec[i];
            int pos = atomicAdd(&cur[rec.x & 127], 1);   // LDS atomic
            int2 o;
            o.x = rec.x >> 7;
            o.y = rec.y;
            csr[bseg + pos] = o;
        }
    }

    // g = dinv * h for this bucket's nodes (coalesced)
    for (int i = tid; i < NPB * F_OUT; i += 256) {
        int idx = c0 * F_OUT + i;
        if (idx < N_NODES * F_OUT) g[idx] = dl[i >> 4] * h[idx];
    }
}

// K6: wave per node — register accumulation. NO atomics, NO LDS in the loop.
// lane (s,j): s = record slot (4-way), j = feature. Gathers are line-coalesced
// (16 lanes per 64B line of g), record reads broadcast. shfl-reduce over s.
__global__ void k_pull2(const int* __restrict__ nodeptr,
                        const int* __restrict__ ncnt,
                        const int2* __restrict__ csr,
                        const float* __restrict__ g,
                        const float* __restrict__ dinv,
                        const float* __restrict__ bias,
                        float* __restrict__ out) {
    int n = blockIdx.x * 4 + (threadIdx.x >> 6);
    if (n >= N_NODES) return;
    int lane = threadIdx.x & 63;
    int s = lane >> 4;
    int j = lane & 15;
    int p0 = nodeptr[n];
    int cnt = ncnt[n];
    float bj = bias[j];
    float acc = 0.0f;
    if (cnt >= 0) {
#pragma unroll 4
        for (int i = s; i < cnt; i += 4) {
            int2 rec = csr[p0 + i];
            acc += g[(size_t)rec.x * F_OUT + j] * __int_as_float(rec.y);
        }
    } else {
        // overflow bucket (unsorted, cl still packed) — correct slow path
        int total = -cnt;
        int cl = n - (n / NPB) * NPB;
        for (int i = s; i < total; i += 4) {
            int2 rec = csr[p0 + i];
            if ((rec.x & 127) == cl)
                acc += g[(size_t)(rec.x >> 7) * F_OUT + j] * __int_as_float(rec.y);
        }
    }
    acc += __shfl_xor(acc, 16);
    acc += __shfl_xor(acc, 32);
    if (s == 0) {
        float dn = dinv[n];
        out[(size_t)n * F_OUT + j] = bj + dn * (g[(size_t)n * F_OUT + j] + acc);
    }
}

// ============ fallback path (R4, proven) ============

#define EDGE_BLOCKS_FB ((N_EDGES + 255) / 256)
__global__ void k_init_fb(float* __restrict__ deg) {
    int i = blockIdx.x * blockDim.x + threadIdx.x;
    if (i < N_NODES) deg[i] = 1.0f;
}
__global__ void k_fused_fb(const int* __restrict__ col, const float* __restrict__ ew,
                           float* __restrict__ deg, const float* __restrict__ x,
                           const float* __restrict__ W, float* __restrict__ h) {
    int b3 = blockIdx.x / 3;
    int r3 = blockIdx.x % 3;
    if (r3 < 2) {
        int e = (b3 * 2 + r3) * 256 + threadIdx.x;
        if (e < N_EDGES) atomicAdd(&deg[col[e]], ew[e]);
    } else {
        __shared__ float Ws[F_IN * F_OUT];
        int tid = threadIdx.x;
        for (int i = tid; i < F_IN * F_OUT; i += 256) Ws[i] = W[i];
        __syncthreads();
        int n = b3 * 16 + (tid >> 4);
        int j = tid & 15;
        if (n >= N_NODES) return;
        const float4* xr = (const float4*)(x + (size_t)n * F_IN);
        float acc = 0.0f;
#pragma unroll
        for (int k4 = 0; k4 < F_IN / 4; ++k4) {
            float4 xv = xr[k4];
            int k = k4 * 4;
            acc += xv.x * Ws[(k + 0) * F_OUT + j];
            acc += xv.y * Ws[(k + 1) * F_OUT + j];
            acc += xv.z * Ws[(k + 2) * F_OUT + j];
            acc += xv.w * Ws[(k + 3) * F_OUT + j];
        }
        h[(size_t)n * F_OUT + j] = acc;
    }
}
__global__ void k_final_fb(float* __restrict__ deg, const float* __restrict__ h,
                           const float* __restrict__ b, float* __restrict__ g,
                           float* __restrict__ out) {
    int i = blockIdx.x * blockDim.x + threadIdx.x;
    int n = i >> 4;
    int j = i & 15;
    if (n >= N_NODES) return;
    float d = rsqrtf(deg[n]);
    if (j == 0) deg[n] = d;
    float gg = d * h[i];
    g[i] = gg;
    out[i] = b[j] + d * gg;
}
__global__ void k_scatter_fb(const int* __restrict__ row, const int* __restrict__ col,
                             const float* __restrict__ ew, const float* __restrict__ dinv,
                             const float* __restrict__ g, float* __restrict__ out) {
    long long tid = (long long)blockIdx.x * blockDim.x + threadIdx.x;
    int e = (int)(tid >> 4);
    int j = (int)(tid & 15);
    if (e >= N_EDGES) return;
    int c = col[e];
    float norm = ew[e] * dinv[c];
    atomicAdd(&out[(size_t)c * F_OUT + j], g[(size_t)row[e] * F_OUT + j] * norm);
}

extern "C" void kernel_launch(void* const* d_in, const int* in_sizes, int n_in,
                              void* d_out, int out_size, void* d_ws, size_t ws_size,
                              hipStream_t stream) {
    const float* x  = (const float*)d_in[0];
    const int*   ei = (const int*)d_in[1];   // [2, N_EDGES] int32
    const float* ew = (const float*)d_in[2];
    const float* W  = (const float*)d_in[3];
    const float* b  = (const float*)d_in[4];
    float* out = (float*)d_out;

    const int* row = ei;            // edge_index[0] = source
    const int* col = ei + N_EDGES;  // edge_index[1] = destination

    char* ws = (char*)d_ws;
    dim3 blk(256);

    if (ws_size >= WS_NEEDED) {
        int*   Tt   = (int*)(ws + OFF_TT);
        int*   ncnt = (int*)(ws + OFF_NCNT);    // aliases Tt (dead after k_bin)
        int*   tot  = (int*)(ws + OFF_TOT);
        int*   base = (int*)(ws + OFF_BASE);
        float* dinv = (float*)(ws + OFF_DINV);
        int*   nptr = (int*)(ws + OFF_NPTR);
        float* h    = (float*)(ws + OFF_HH);
        float* g    = (float*)(ws + OFF_GG);
        int2*  csr  = (int2*)(ws + OFF_CSR);

        k_hist_gemm<<<NSEG + GEMM_BLOCKS, blk, 0, stream>>>(col, Tt, x, W, h);
        k_scan_a<<<NBUCK / 4, blk, 0, stream>>>(Tt, tot);
        k_scan_b<<<1, blk, 0, stream>>>(tot, base);
        k_bin<<<NSEG, 512, 0, stream>>>(row, col, ew, Tt, base, csr);
        k_sort<<<NBUCK, blk, 0, stream>>>(base, tot, csr, h, dinv, g, nptr, ncnt);
        k_pull2<<<(N_NODES + 3) / 4, blk, 0, stream>>>(nptr, ncnt, csr, g, dinv, b, out);
    } else {
        float* deg = (float*)ws;
        float* h   = (float*)(ws + (1u << 20));
        float* g   = (float*)(ws + (8u << 20));
        k_init_fb<<<(N_NODES + 255) / 256, blk, 0, stream>>>(deg);
        k_fused_fb<<<EDGE_BLOCKS_FB + GEMM_BLOCKS, blk, 0, stream>>>(col, ew, deg, x, W, h);
        k_final_fb<<<(N_NODES * F_OUT + 255) / 256, blk, 0, stream>>>(deg, h, b, g, out);
        long long total = (long long)N_EDGES * F_OUT;
        k_scatter_fb<<<(unsigned)((total + 255) / 256), blk, 0, stream>>>(row, col, ew, deg, g, out);
    }
}